// Round 4
// baseline (1086.711 us; speedup 1.0000x reference)
//
#include <hip/hip_runtime.h>

typedef unsigned int u32;

#define NB 4
#define NQ 8192
#define QB 64   // queries per block; 4 waves split each candidate array 4-ways

struct D4 { double x, y, z, w; };

__device__ __forceinline__ bool lexless(double da, int ia, double db, int ib) {
  return (da < db) || (da == db && ia < ib);
}

struct Smem {
  D4     qp[QB];             // query x,y,z,|p|^2 (f64)
  D4     tile[512];          // candidate tile x,y,z,|k|^2 (f64)
  double t3d[3][QB][4][3];   // per-level, per-query, per-part top3 dists
  int    t3i[3][QB][4][3];   // matching indices
  double mmin[QB][4];        // per-part mask min d2
  float  wv[96];             // folded w_cls @ w_fc
  float  part[QB][3];        // per-level partial pred
};

// Scan one candidate array. All selection arithmetic in f64: for bf16-valued
// inputs the expansion (p2 + k2) - 2*dot is EXACT in f64 (16-bit-mantissa
// products, alignments < 53 bits), so ordering matches any higher-precision
// reference. Stable tie-break: within a part indices ascend and a tie never
// displaces (strict <); cross-part merge uses (d, idx) lexicographic order.
template <bool MASK>
__device__ __forceinline__ void scan_array(
    const float* __restrict__ src, int M, int b,
    double qx, double qy, double qz, double qn,
    int wpart, int tid, Smem& s,
    double& e0d, double& e1d, double& e2d,
    int& e0i, int& e1i, int& e2i, double& dmin) {
  const double INF = __builtin_inf();
  e0d = INF; e1d = INF; e2d = INF;
  e0i = 0;   e1i = 0;   e2i = 0;
  dmin = INF;
  const int off = wpart * 128;
  for (int t0 = 0; t0 < M; t0 += 512) {
    __syncthreads();
    {
      // stage 512 candidates: each thread converts 2 points to f64 + |k|^2
      int pi = t0 + 2 * tid;
      const float* p = src + (size_t)(b * M + pi) * 3;
      double x0 = (double)p[0], y0 = (double)p[1], z0 = (double)p[2];
      double x1 = (double)p[3], y1 = (double)p[4], z1 = (double)p[5];
      D4 c0 = {x0, y0, z0, x0 * x0 + y0 * y0 + z0 * z0};
      D4 c1 = {x1, y1, z1, x1 * x1 + y1 * y1 + z1 * z1};
      s.tile[2 * tid]     = c0;
      s.tile[2 * tid + 1] = c1;
    }
    __syncthreads();
#pragma unroll 4
    for (int j = 0; j < 128; ++j) {
      D4 c = s.tile[off + j];  // wave-uniform address -> LDS broadcast
      double dot = qx * c.x + qy * c.y + qz * c.z;
      double d = (qn + c.w) - 2.0 * dot;
      if (MASK) {
        dmin = fmin(dmin, d);
      } else if (d < e2d) {    // strict: tie with 3rd-best never displaces
        int idx = t0 + off + j;
        if (d < e0d) {
          e2d = e1d; e2i = e1i; e1d = e0d; e1i = e0i; e0d = d; e0i = idx;
        } else if (d < e1d) {  // tie with e0 falls through -> after e0 (stable)
          e2d = e1d; e2i = e1i; e1d = d; e1i = idx;
        } else {
          e2d = d; e2i = idx;
        }
      }
    }
  }
}

__global__ __launch_bounds__(256, 2) void fused_kernel(
    const float* __restrict__ pts,
    const float* __restrict__ k2p, const float* __restrict__ f2,
    const float* __restrict__ k3p, const float* __restrict__ f3,
    const float* __restrict__ k4p, const float* __restrict__ f4,
    const float* __restrict__ mmp,
    const float* __restrict__ wfc, const float* __restrict__ wcls,
    float* __restrict__ out) {
  __shared__ Smem s;
  const int tid = threadIdx.x;
  const int b = blockIdx.y;
  const int q0 = blockIdx.x * QB;
  const int qloc = tid & 63;
  const int wpart = tid >> 6;   // wave-uniform part id, 4 parts

  // phase 1: load the 64 queries (f64); threads 64..159 fold w_cls @ w_fc
  if (tid < QB) {
    int gq = b * NQ + q0 + tid;
    double x = (double)pts[3 * gq];
    double y = (double)pts[3 * gq + 1];
    double z = (double)pts[3 * gq + 2];
    D4 q = {x, y, z, x * x + y * y + z * z};
    s.qp[tid] = q;
  } else if (tid < 64 + 96) {
    int t = tid - 64;
    float acc = 0.f;
    for (int j = 0; j < 64; ++j) acc += wcls[j] * wfc[j * 96 + t];
    s.wv[t] = acc;
  }
  __syncthreads();
  const D4 qp = s.qp[qloc];

  // phase 2: scan the three known-point arrays + the match array
  const float* lsrc[3] = {k2p, k3p, k4p};
  const int    lM[3]   = {8192, 4096, 2048};
#pragma unroll 1
  for (int l = 0; l < 3; ++l) {
    double e0d, e1d, e2d, dm; int e0i, e1i, e2i;
    scan_array<false>(lsrc[l], lM[l], b, qp.x, qp.y, qp.z, qp.w,
                      wpart, tid, s, e0d, e1d, e2d, e0i, e1i, e2i, dm);
    s.t3d[l][qloc][wpart][0] = e0d; s.t3i[l][qloc][wpart][0] = e0i;
    s.t3d[l][qloc][wpart][1] = e1d; s.t3i[l][qloc][wpart][1] = e1i;
    s.t3d[l][qloc][wpart][2] = e2d; s.t3i[l][qloc][wpart][2] = e2i;
  }
  {
    double e0d, e1d, e2d, dm; int e0i, e1i, e2i;
    scan_array<true>(mmp, 4096, b, qp.x, qp.y, qp.z, qp.w,
                     wpart, tid, s, e0d, e1d, e2d, e0i, e1i, e2i, dm);
    s.mmin[qloc][wpart] = dm;
  }
  __syncthreads();

  // phase 3: merge partials, weights (f64), gather feats, folded FC / mask
  const int gqbase = b * NQ + q0;
  if (tid < 192) {
    const int lvl = tid >> 6;   // wave-uniform
    const int q = tid & 63;
    double e0d = s.t3d[lvl][q][0][0], e1d = s.t3d[lvl][q][0][1], e2d = s.t3d[lvl][q][0][2];
    int    e0i = s.t3i[lvl][q][0][0], e1i = s.t3i[lvl][q][0][1], e2i = s.t3i[lvl][q][0][2];
#pragma unroll
    for (int p = 1; p < 4; ++p) {
#pragma unroll
      for (int r = 0; r < 3; ++r) {
        double d = s.t3d[lvl][q][p][r];
        int    i = s.t3i[lvl][q][p][r];
        if (lexless(d, i, e2d, e2i)) {
          if (lexless(d, i, e0d, e0i)) {
            e2d = e1d; e2i = e1i; e1d = e0d; e1i = e0i; e0d = d; e0i = i;
          } else if (lexless(d, i, e1d, e1i)) {
            e2d = e1d; e2i = e1i; e1d = d; e1i = i;
          } else {
            e2d = d; e2i = i;
          }
        }
      }
    }
    double d0 = fmax(e0d, 0.0), d1 = fmax(e1d, 0.0), d2v = fmax(e2d, 0.0);
    double r0 = 1.0 / (d0 + 1e-8);
    double r1 = 1.0 / (d1 + 1e-8);
    double r2 = 1.0 / (d2v + 1e-8);
    double sum = (r0 + r1) + r2;
    float wa = (float)(r0 / sum), wb = (float)(r1 / sum), wc = (float)(r2 / sum);

    const float* fp = (lvl == 0) ? f2 : ((lvl == 1) ? f3 : f4);
    const int    M  = (lvl == 0) ? 8192 : ((lvl == 1) ? 4096 : 2048);
    const float* g0 = fp + (size_t)(b * M + e0i) * 32;
    const float* g1 = fp + (size_t)(b * M + e1i) * 32;
    const float* g2 = fp + (size_t)(b * M + e2i) * 32;
    float acc = 0.f;
#pragma unroll
    for (int wd = 0; wd < 32; ++wd) {
      float v = (wa * g0[wd] + wb * g1[wd]) + wc * g2[wd];
      acc += s.wv[lvl * 32 + wd] * v;
    }
    s.part[q][lvl] = acc;
  } else {
    const int q = tid - 192;
    double dm = fmin(fmin(s.mmin[q][0], s.mmin[q][1]),
                     fmin(s.mmin[q][2], s.mmin[q][3]));
    // d2 < 0.25 == sqrt(max(d2,0)) < 0.5 (monotone, both strict; exact d2)
    out[NB * NQ + gqbase + q] = (dm < 0.25) ? 1.0f : 0.0f;
  }
  __syncthreads();
  if (tid < QB) {
    float pred = (s.part[tid][0] + s.part[tid][1]) + s.part[tid][2];
    out[gqbase + tid] = pred;
  }
}

extern "C" void kernel_launch(void* const* d_in, const int* in_sizes, int n_in,
                              void* d_out, int out_size, void* d_ws, size_t ws_size,
                              hipStream_t stream) {
  const float* pts    = (const float*)d_in[0];
  const float* known2 = (const float*)d_in[1];
  const float* feats2 = (const float*)d_in[2];
  const float* known3 = (const float*)d_in[3];
  const float* feats3 = (const float*)d_in[4];
  const float* known4 = (const float*)d_in[5];
  const float* feats4 = (const float*)d_in[6];
  const float* match  = (const float*)d_in[7];
  const float* wfc    = (const float*)d_in[8];
  const float* wcls   = (const float*)d_in[9];
  (void)d_ws; (void)ws_size;  // workspace intentionally unused

  hipLaunchKernelGGL(fused_kernel, dim3(NQ / QB, NB), dim3(256), 0, stream,
                     pts, known2, feats2, known3, feats3, known4, feats4,
                     match, wfc, wcls, (float*)d_out);
}